// Round 1
// baseline (936.241 us; speedup 1.0000x reference)
//
#include <hip/hip_runtime.h>

#define NN 50000
#define EE 800000
#define NEP (EE + NN)

// ---------------- CSR build (counting sort by dst) ----------------
__global__ __launch_bounds__(256) void k_count(const int* __restrict__ ei, int* __restrict__ counts) {
    int e = blockIdx.x * 256 + threadIdx.x;
    if (e >= NEP) return;
    int dst = (e < EE) ? ei[EE + e] : (e - EE);   // self-loops appended
    atomicAdd(&counts[dst], 1);
}

__global__ __launch_bounds__(1024) void k_scan(const int* __restrict__ counts,
                                               int* __restrict__ indptr, int* __restrict__ cursor) {
    __shared__ int wsum[16];
    __shared__ int carry_s;
    int tid = threadIdx.x, lane = tid & 63, wid = tid >> 6;
    if (tid == 0) carry_s = 0;
    __syncthreads();
    for (int base = 0; base < NN; base += 1024) {
        int i = base + tid;
        int v = (i < NN) ? counts[i] : 0;
        int s = v;
        #pragma unroll
        for (int d = 1; d < 64; d <<= 1) { int t = __shfl_up(s, d); if (lane >= d) s += t; }
        if (lane == 63) wsum[wid] = s;
        __syncthreads();
        if (wid == 0) {
            int ws = (lane < 16) ? wsum[lane] : 0;
            #pragma unroll
            for (int d = 1; d < 16; d <<= 1) { int t = __shfl_up(ws, d); if (lane >= d) ws += t; }
            if (lane < 16) wsum[lane] = ws;
        }
        __syncthreads();
        int off = carry_s + (wid > 0 ? wsum[wid - 1] : 0);
        int excl = off + s - v;
        if (i < NN) { indptr[i] = excl; cursor[i] = excl; }
        __syncthreads();
        if (tid == 1023) carry_s = off + s;
        __syncthreads();
    }
    if (tid == 0) indptr[NN] = carry_s;
}

__global__ __launch_bounds__(256) void k_scatter(const int* __restrict__ ei,
                                                 int* __restrict__ cursor, int* __restrict__ srcs) {
    int e = blockIdx.x * 256 + threadIdx.x;
    if (e >= NEP) return;
    int src, dst;
    if (e < EE) { src = ei[e]; dst = ei[EE + e]; }
    else        { src = e - EE; dst = src; }
    int pos = atomicAdd(&cursor[dst], 1);
    srcs[pos] = src;
}

// ---------------- fp32 register-tiled GEMM: Y[NN,NOUT] = X[NN,K] @ W[K,NOUT] ----------------
template<int K, int NOUT>
__global__ __launch_bounds__(256) void k_gemm(const float* __restrict__ X, const float* __restrict__ Wm,
                                              float* __restrict__ Y) {
    __shared__ float As[16][132];   // [k][row], +4 pad
    __shared__ float Bs[16][64];    // [k][col]
    const int bm = blockIdx.x * 128, bn = blockIdx.y * 64;
    const int tid = threadIdx.x;
    const int tx = tid & 15, ty = tid >> 4;
    float acc[8][4] = {};
    for (int k0 = 0; k0 < K; k0 += 16) {
        #pragma unroll
        for (int i = 0; i < 2; i++) {
            int idx = tid + i * 256;
            int r = idx >> 2, c4 = (idx & 3) << 2;
            float4 v = make_float4(0.f, 0.f, 0.f, 0.f);
            int gr = bm + r;
            if (gr < NN) v = *(const float4*)&X[(size_t)gr * K + k0 + c4];
            As[c4 + 0][r] = v.x; As[c4 + 1][r] = v.y; As[c4 + 2][r] = v.z; As[c4 + 3][r] = v.w;
        }
        {
            int r = tid >> 4, c4 = (tid & 15) << 2;
            float4 v = make_float4(0.f, 0.f, 0.f, 0.f);
            if (bn + c4 < NOUT) v = *(const float4*)&Wm[(size_t)(k0 + r) * NOUT + bn + c4];
            *(float4*)&Bs[r][c4] = v;
        }
        __syncthreads();
        #pragma unroll
        for (int kk = 0; kk < 16; kk++) {
            float4 a0 = *(const float4*)&As[kk][ty * 8];
            float4 a1 = *(const float4*)&As[kk][ty * 8 + 4];
            float4 b  = *(const float4*)&Bs[kk][tx * 4];
            float av[8] = {a0.x, a0.y, a0.z, a0.w, a1.x, a1.y, a1.z, a1.w};
            float bv[4] = {b.x, b.y, b.z, b.w};
            #pragma unroll
            for (int i = 0; i < 8; i++)
                #pragma unroll
                for (int j = 0; j < 4; j++)
                    acc[i][j] += av[i] * bv[j];
        }
        __syncthreads();
    }
    #pragma unroll
    for (int i = 0; i < 8; i++) {
        int gr = bm + ty * 8 + i;
        if (gr >= NN) continue;
        int gc = bn + tx * 4;
        if (gc + 3 < NOUT) {
            float4 v = make_float4(acc[i][0], acc[i][1], acc[i][2], acc[i][3]);
            *(float4*)&Y[(size_t)gr * NOUT + gc] = v;
        } else {
            #pragma unroll
            for (int j = 0; j < 4; j++)
                if (gc + j < NOUT) Y[(size_t)gr * NOUT + gc + j] = acc[i][j];
        }
    }
}

// ---------------- per-node attention logits e_src/e_dst ----------------
template<int C, int RS>
__global__ __launch_bounds__(256) void k_edot(const float* __restrict__ Hb,
        const float* __restrict__ a_src, const float* __restrict__ a_dst,
        float* __restrict__ es, float* __restrict__ ed) {
    const int gw = (blockIdx.x * 256 + threadIdx.x) >> 6;   // one wave per node
    const int lane = threadIdx.x & 63;
    if (gw >= NN) return;
    const float* __restrict__ row = Hb + (size_t)gw * RS;
    #pragma unroll
    for (int h = 0; h < 4; h++) {
        float s1 = 0.f, s2 = 0.f;
        if (lane < C) {
            float v = row[h * C + lane];
            s1 = v * a_src[h * C + lane];
            s2 = v * a_dst[h * C + lane];
        }
        #pragma unroll
        for (int d = 32; d; d >>= 1) { s1 += __shfl_down(s1, d); s2 += __shfl_down(s2, d); }
        if (lane == 0) { es[gw * 4 + h] = s1; ed[gw * 4 + h] = s2; }
    }
}

// ---------------- fused segment-softmax + aggregation (layers 0/1, 256-wide rows) ----------------
__global__ __launch_bounds__(256) void k_agg(const float* __restrict__ Hb,
        const float* __restrict__ es, const float* __restrict__ ed,
        const int* __restrict__ indptr, const int* __restrict__ srcs,
        float* __restrict__ outp) {
    __shared__ float w_s[256][4];
    __shared__ int   src_s[256];
    __shared__ float z_s[4];
    const int n = blockIdx.x, tid = threadIdx.x;
    const int e0 = indptr[n], e1 = indptr[n + 1];
    const int head = tid >> 6, c = tid & 63;
    if (tid < 4) z_s[tid] = 0.f;
    float acc = 0.f;
    const float* __restrict__ Hh = Hb + head * 64 + c;
    for (int base = e0; base < e1; base += 256) {
        const int cnt = min(256, e1 - base);
        __syncthreads();                       // protect LDS reuse (and z_s init)
        for (int i = tid; i < cnt; i += 256) src_s[i] = srcs[base + i];
        __syncthreads();
        for (int it = tid; it < cnt * 4; it += 256) {
            int sl = it >> 2, h = it & 3;
            float e = es[src_s[sl] * 4 + h] + ed[n * 4 + h];
            e = (e > 0.f) ? e : 0.2f * e;      // leaky relu
            float wv = expf(e);                // no max-shift needed (|e| small)
            w_s[sl][h] = wv;
            atomicAdd(&z_s[h], wv);
        }
        __syncthreads();
        for (int sl = 0; sl < cnt; sl++)
            acc += w_s[sl][head] * Hh[(size_t)src_s[sl] * 256];
    }
    __syncthreads();
    outp[(size_t)n * 256 + tid] = acc / (z_s[head] + 1e-16f);
}

// ---------------- layer 2: aggregation + head-mean + bias + log_softmax ----------------
__global__ __launch_bounds__(256) void k_agg2(const float* __restrict__ Hb,
        const float* __restrict__ es, const float* __restrict__ ed,
        const int* __restrict__ indptr, const int* __restrict__ srcs,
        const float* __restrict__ b2, float* __restrict__ outp) {
    __shared__ float w_s[256][4];
    __shared__ int   src_s[256];
    __shared__ float z_s[4];
    __shared__ float vals[160];
    const int n = blockIdx.x, tid = threadIdx.x;
    const int e0 = indptr[n], e1 = indptr[n + 1];
    if (tid < 4) z_s[tid] = 0.f;
    float acc = 0.f;
    const int headc = tid / 40;                // valid for tid<160
    for (int base = e0; base < e1; base += 256) {
        const int cnt = min(256, e1 - base);
        __syncthreads();
        for (int i = tid; i < cnt; i += 256) src_s[i] = srcs[base + i];
        __syncthreads();
        for (int it = tid; it < cnt * 4; it += 256) {
            int sl = it >> 2, h = it & 3;
            float e = es[src_s[sl] * 4 + h] + ed[n * 4 + h];
            e = (e > 0.f) ? e : 0.2f * e;
            float wv = expf(e);
            w_s[sl][h] = wv;
            atomicAdd(&z_s[h], wv);
        }
        __syncthreads();
        if (tid < 160) {
            for (int sl = 0; sl < cnt; sl++)
                acc += w_s[sl][headc] * Hb[(size_t)src_s[sl] * 160 + tid];
        }
    }
    __syncthreads();
    if (tid < 160) vals[tid] = acc / (z_s[headc] + 1e-16f);
    __syncthreads();
    if (tid < 64) {
        float sv = 0.f, v = -1e30f;
        if (tid < 40) {
            sv = 0.25f * (vals[tid] + vals[40 + tid] + vals[80 + tid] + vals[120 + tid]) + b2[tid];
            v = sv;
        }
        float m = v;
        #pragma unroll
        for (int d = 32; d; d >>= 1) m = fmaxf(m, __shfl_down(m, d));
        m = __shfl(m, 0);
        float ex = (tid < 40) ? expf(sv - m) : 0.f;
        float s = ex;
        #pragma unroll
        for (int d = 32; d; d >>= 1) s += __shfl_down(s, d);
        s = __shfl(s, 0);
        if (tid < 40) outp[(size_t)n * 40 + tid] = sv - m - logf(s);
    }
}

// ---------------- BatchNorm (training-mode stats) + ELU, in place ----------------
__global__ __launch_bounds__(256) void k_bnstats(const float* __restrict__ X,
        float* __restrict__ sum, float* __restrict__ sumsq) {
    const int col = threadIdx.x;
    float s = 0.f, q = 0.f;
    for (int r = blockIdx.x; r < NN; r += gridDim.x) {
        float v = X[(size_t)r * 256 + col];
        s += v; q += v * v;
    }
    atomicAdd(&sum[col], s);
    atomicAdd(&sumsq[col], q);
}

__global__ __launch_bounds__(256) void k_bnapply(float* __restrict__ X,
        const float* __restrict__ sum, const float* __restrict__ sumsq,
        const float* __restrict__ g, const float* __restrict__ beta) {
    const int col = threadIdx.x;
    const float inv = 1.f / (float)NN;
    float mu = sum[col] * inv;
    float var = sumsq[col] * inv - mu * mu;
    float sc = rsqrtf(var + 1e-5f) * g[col];
    float sh = beta[col] - mu * sc;             // GAT bias b cancels under BN
    for (int r = blockIdx.x; r < NN; r += gridDim.x) {
        float v = X[(size_t)r * 256 + col] * sc + sh;
        X[(size_t)r * 256 + col] = (v > 0.f) ? v : expm1f(v);   // ELU
    }
}

extern "C" void kernel_launch(void* const* d_in, const int* in_sizes, int n_in,
                              void* d_out, int out_size, void* d_ws, size_t ws_size,
                              hipStream_t stream) {
    const float* x   = (const float*)d_in[0];
    const int*   ei  = (const int*)d_in[1];
    const float* W0  = (const float*)d_in[2];
    const float* as0 = (const float*)d_in[3];
    const float* ad0 = (const float*)d_in[4];
    // d_in[5] = b0 (cancels under BN)
    const float* g0  = (const float*)d_in[6];
    const float* be0 = (const float*)d_in[7];
    const float* W1  = (const float*)d_in[8];
    const float* as1 = (const float*)d_in[9];
    const float* ad1 = (const float*)d_in[10];
    // d_in[11] = b1 (cancels under BN)
    const float* g1  = (const float*)d_in[12];
    const float* be1 = (const float*)d_in[13];
    const float* W2  = (const float*)d_in[14];
    const float* as2 = (const float*)d_in[15];
    const float* ad2 = (const float*)d_in[16];
    const float* b2  = (const float*)d_in[17];
    float* out = (float*)d_out;

    char* w = (char*)d_ws;
    size_t off = 0;
    auto take = [&](size_t bytes) -> void* {
        off = (off + 255) & ~(size_t)255;
        void* p = w + off; off += bytes; return p;
    };
    float* A      = (float*)take((size_t)NN * 256 * 4);   // h buffer
    float* Bb     = (float*)take((size_t)NN * 256 * 4);   // node features
    float* es     = (float*)take((size_t)NN * 4 * 4);
    float* ed     = (float*)take((size_t)NN * 4 * 4);
    int*   counts = (int*)take((size_t)NN * 4);
    int*   indptr = (int*)take((size_t)(NN + 1) * 4);
    int*   cursor = (int*)take((size_t)NN * 4);
    int*   srcs   = (int*)take((size_t)NEP * 4);
    float* bns    = (float*)take(512 * 4);                // sum[256] | sumsq[256]

    const int gE = (NEP + 255) / 256;
    hipMemsetAsync(counts, 0, (size_t)NN * 4, stream);
    k_count  <<<gE, 256, 0, stream>>>(ei, counts);
    k_scan   <<<1, 1024, 0, stream>>>(counts, indptr, cursor);
    k_scatter<<<gE, 256, 0, stream>>>(ei, cursor, srcs);

    const int gM = (NN + 127) / 128;
    const int gW = (NN + 3) / 4;

    // ---- layer 0 ----
    k_gemm<128, 256><<<dim3(gM, 4), 256, 0, stream>>>(x, W0, A);
    k_edot<64, 256><<<gW, 256, 0, stream>>>(A, as0, ad0, es, ed);
    k_agg<<<NN, 256, 0, stream>>>(A, es, ed, indptr, srcs, Bb);
    hipMemsetAsync(bns, 0, 2048, stream);
    k_bnstats<<<512, 256, 0, stream>>>(Bb, bns, bns + 256);
    k_bnapply<<<1024, 256, 0, stream>>>(Bb, bns, bns + 256, g0, be0);

    // ---- layer 1 ----
    k_gemm<256, 256><<<dim3(gM, 4), 256, 0, stream>>>(Bb, W1, A);
    k_edot<64, 256><<<gW, 256, 0, stream>>>(A, as1, ad1, es, ed);
    k_agg<<<NN, 256, 0, stream>>>(A, es, ed, indptr, srcs, Bb);
    hipMemsetAsync(bns, 0, 2048, stream);
    k_bnstats<<<512, 256, 0, stream>>>(Bb, bns, bns + 256);
    k_bnapply<<<1024, 256, 0, stream>>>(Bb, bns, bns + 256, g1, be1);

    // ---- layer 2 ----
    k_gemm<256, 160><<<dim3(gM, 3), 256, 0, stream>>>(Bb, W2, A);
    k_edot<40, 160><<<gW, 256, 0, stream>>>(A, as2, ad2, es, ed);
    k_agg2<<<NN, 256, 0, stream>>>(A, es, ed, indptr, srcs, b2, out);
}

// Round 2
// 726.529 us; speedup vs baseline: 1.2886x; 1.2886x over previous
//
#include <hip/hip_runtime.h>

#define NN 50000
#define EE 800000
#define NEP (EE + NN)

typedef float f32x4 __attribute__((ext_vector_type(4)));
typedef short bf16x8 __attribute__((ext_vector_type(8)));

__device__ inline float bf2f(unsigned short u) {
    union { unsigned int i; float f; } v; v.i = ((unsigned int)u) << 16; return v.f;
}
__device__ inline unsigned short f2bf(float f) {
    unsigned int x = __builtin_bit_cast(unsigned int, f);
    unsigned int r = x + 0x7FFFu + ((x >> 16) & 1u);
    return (unsigned short)(r >> 16);
}

// ---------------- CSR build (counting sort by dst) ----------------
__global__ __launch_bounds__(256) void k_count(const int* __restrict__ ei, int* __restrict__ counts) {
    int e = blockIdx.x * 256 + threadIdx.x;
    if (e >= NEP) return;
    int dst = (e < EE) ? ei[EE + e] : (e - EE);
    atomicAdd(&counts[dst], 1);
}

__global__ __launch_bounds__(1024) void k_scan(const int* __restrict__ counts,
                                               int* __restrict__ indptr, int* __restrict__ cursor) {
    __shared__ int wsum[16];
    __shared__ int carry_s;
    int tid = threadIdx.x, lane = tid & 63, wid = tid >> 6;
    if (tid == 0) carry_s = 0;
    __syncthreads();
    for (int base = 0; base < NN; base += 1024) {
        int i = base + tid;
        int v = (i < NN) ? counts[i] : 0;
        int s = v;
        #pragma unroll
        for (int d = 1; d < 64; d <<= 1) { int t = __shfl_up(s, d); if (lane >= d) s += t; }
        if (lane == 63) wsum[wid] = s;
        __syncthreads();
        if (wid == 0) {
            int ws = (lane < 16) ? wsum[lane] : 0;
            #pragma unroll
            for (int d = 1; d < 16; d <<= 1) { int t = __shfl_up(ws, d); if (lane >= d) ws += t; }
            if (lane < 16) wsum[lane] = ws;
        }
        __syncthreads();
        int off = carry_s + (wid > 0 ? wsum[wid - 1] : 0);
        int excl = off + s - v;
        if (i < NN) { indptr[i] = excl; cursor[i] = excl; }
        __syncthreads();
        if (tid == 1023) carry_s = off + s;
        __syncthreads();
    }
    if (tid == 0) indptr[NN] = carry_s;
}

__global__ __launch_bounds__(256) void k_scatter(const int* __restrict__ ei,
                                                 int* __restrict__ cursor, int* __restrict__ srcs) {
    int e = blockIdx.x * 256 + threadIdx.x;
    if (e >= NEP) return;
    int src, dst;
    if (e < EE) { src = ei[e]; dst = ei[EE + e]; }
    else        { src = e - EE; dst = src; }
    int pos = atomicAdd(&cursor[dst], 1);
    srcs[pos] = src;
}

// ---------------- fp32 -> bf16 convert (x) ----------------
__global__ __launch_bounds__(256) void k_f2b(const float* __restrict__ X,
                                             unsigned short* __restrict__ Y, int n4) {
    int i = blockIdx.x * 256 + threadIdx.x;
    if (i >= n4) return;
    float4 v = ((const float4*)X)[i];
    ushort4 o;
    o.x = f2bf(v.x); o.y = f2bf(v.y); o.z = f2bf(v.z); o.w = f2bf(v.w);
    ((ushort4*)Y)[i] = o;
}

// ---------------- W[k][c] -> Wt[c][k] bf16 (pad cols to NOP with zeros) ----------------
__global__ __launch_bounds__(256) void k_wt(const float* __restrict__ W,
                                            unsigned short* __restrict__ Wt,
                                            int K, int NO, int NOP) {
    int idx = blockIdx.x * 256 + threadIdx.x;
    if (idx >= NOP * K) return;
    int c = idx / K, k = idx - c * K;
    float v = (c < NO) ? W[(size_t)k * NO + c] : 0.f;
    Wt[idx] = f2bf(v);
}

// ---------------- bf16 MFMA GEMM: Y[NN,NOUTP](bf16) = Xb[NN,K](bf16) @ Wt^T ----------------
// Wt is [NOUTP][K] row-major (i.e. W transposed). Block = 64Mx64N, 4 waves (2Mx2N),
// each wave 32x32 via 2x2 fragments of 16x16x32. A panel staged whole-K in LDS with
// XOR swizzle (granule ^= row&7) to kill the 512B-stride bank conflict.
template<int K, int NOUTP>
__global__ __launch_bounds__(256) void k_gemm(const unsigned short* __restrict__ Xb,
                                              const unsigned short* __restrict__ Wt,
                                              unsigned short* __restrict__ Y) {
    constexpr int G = K / 8;                       // 16B granules per row
    __shared__ __attribute__((aligned(16))) unsigned short As[64 * K];
    const int bm = blockIdx.x * 64, bn = blockIdx.y * 64;
    const int tid = threadIdx.x, lane = tid & 63, wid = tid >> 6;
    const int wm = wid >> 1, wn = wid & 1;
    const int l15 = lane & 15, l4 = lane >> 4;

    // preload B fragments for entire K into registers (Wt rows are contiguous in k)
    bf16x8 bfr[2][K / 32];
    #pragma unroll
    for (int n = 0; n < 2; n++) {
        const int col = bn + wn * 32 + n * 16 + l15;
        #pragma unroll
        for (int ks = 0; ks < K / 32; ks++)
            bfr[n][ks] = *(const bf16x8*)&Wt[(size_t)col * K + ks * 32 + l4 * 8];
    }

    // stage A panel (64 rows x K) with swizzle
    #pragma unroll
    for (int i = 0; i < (64 * G) / 256; i++) {
        int p = tid + 256 * i;
        int row = p / G, gi = p % G;
        int grow = bm + row; if (grow >= NN) grow = 0;
        bf16x8 v = *(const bf16x8*)&Xb[(size_t)grow * K + gi * 8];
        *(bf16x8*)&As[row * K + (gi ^ (row & 7)) * 8] = v;
    }
    __syncthreads();

    f32x4 acc[2][2];
    #pragma unroll
    for (int m = 0; m < 2; m++)
        #pragma unroll
        for (int n = 0; n < 2; n++) acc[m][n] = (f32x4)0.f;

    #pragma unroll
    for (int ks = 0; ks < K / 32; ks++) {
        #pragma unroll
        for (int m = 0; m < 2; m++) {
            const int r = wm * 32 + m * 16 + l15;
            const int pg = ((ks << 2) + l4) ^ (r & 7);
            bf16x8 af = *(const bf16x8*)&As[r * K + pg * 8];
            #pragma unroll
            for (int n = 0; n < 2; n++)
                acc[m][n] = __builtin_amdgcn_mfma_f32_16x16x32_bf16(af, bfr[n][ks], acc[m][n], 0, 0, 0);
        }
    }

    // epilogue: C/D layout col=lane&15, row=(lane>>4)*4+reg
    #pragma unroll
    for (int m = 0; m < 2; m++) {
        const int row0 = bm + wm * 32 + m * 16 + l4 * 4;
        #pragma unroll
        for (int n = 0; n < 2; n++) {
            const int col = bn + wn * 32 + n * 16 + l15;
            #pragma unroll
            for (int j = 0; j < 4; j++) {
                int gr = row0 + j;
                if (gr < NN) Y[(size_t)gr * NOUTP + col] = f2bf(acc[m][n][j]);
            }
        }
    }
}

// ---------------- attention logits, layers 0/1 (row stride 256, one wave/node) ----------------
__global__ __launch_bounds__(256) void k_edot01(const unsigned short* __restrict__ H,
        const float* __restrict__ a_src, const float* __restrict__ a_dst,
        float* __restrict__ es, float* __restrict__ ed) {
    const int gw = (blockIdx.x * 256 + threadIdx.x) >> 6;
    const int lane = threadIdx.x & 63;
    if (gw >= NN) return;
    const int head = lane >> 4;
    ushort4 hv = *(const ushort4*)&H[(size_t)gw * 256 + lane * 4];
    float s1 = 0.f, s2 = 0.f;
    const unsigned short hvv[4] = {hv.x, hv.y, hv.z, hv.w};
    #pragma unroll
    for (int j = 0; j < 4; j++) {
        float v = bf2f(hvv[j]);
        s1 += v * a_src[lane * 4 + j];
        s2 += v * a_dst[lane * 4 + j];
    }
    #pragma unroll
    for (int d = 1; d < 16; d <<= 1) { s1 += __shfl_xor(s1, d); s2 += __shfl_xor(s2, d); }
    if ((lane & 15) == 0) { es[gw * 4 + head] = s1; ed[gw * 4 + head] = s2; }
}

// ---------------- attention logits, layer 2 (row stride 192, 160 cols) ----------------
__global__ __launch_bounds__(256) void k_edot2(const unsigned short* __restrict__ H2,
        const float* __restrict__ a_src, const float* __restrict__ a_dst,
        float* __restrict__ es, float* __restrict__ ed) {
    const int gw = (blockIdx.x * 256 + threadIdx.x) >> 6;
    const int lane = threadIdx.x & 63;
    if (gw >= NN) return;
    const int h = lane >> 4, g = lane & 15;
    float s1 = 0.f, s2 = 0.f;
    if (g < 10) {
        ushort4 hv = *(const ushort4*)&H2[(size_t)gw * 192 + h * 40 + g * 4];
        const unsigned short hvv[4] = {hv.x, hv.y, hv.z, hv.w};
        #pragma unroll
        for (int j = 0; j < 4; j++) {
            float v = bf2f(hvv[j]);
            s1 += v * a_src[h * 40 + g * 4 + j];
            s2 += v * a_dst[h * 40 + g * 4 + j];
        }
    }
    #pragma unroll
    for (int d = 1; d < 16; d <<= 1) { s1 += __shfl_xor(s1, d); s2 += __shfl_xor(s2, d); }
    if (g == 0) { es[gw * 4 + h] = s1; ed[gw * 4 + h] = s2; }
}

// ---------------- fused segment-softmax + aggregation, layers 0/1 ----------------
// One wave per node: lane covers 4 cols (8B bf16 load), head = lane>>4.
// Weight is lane-redundant within a head => z needs no cross-lane reduce.
__global__ __launch_bounds__(256) void k_agg(const unsigned short* __restrict__ H,
        const float* __restrict__ es, const float* __restrict__ ed,
        const int* __restrict__ indptr, const int* __restrict__ srcs,
        float* __restrict__ outp) {
    const int wid = threadIdx.x >> 6, lane = threadIdx.x & 63;
    const int n = blockIdx.x * 4 + wid;
    if (n >= NN) return;
    const int head = lane >> 4;
    const float edh = ed[n * 4 + head];
    const int e0 = indptr[n], e1 = indptr[n + 1];
    float z = 0.f, a0 = 0.f, a1 = 0.f, a2 = 0.f, a3 = 0.f;
    const unsigned short* Hp = H + lane * 4;
    for (int e = e0; e < e1; ++e) {
        int src = srcs[e];
        float ev = es[src * 4 + head] + edh;
        ev = (ev > 0.f) ? ev : 0.2f * ev;
        float w = __expf(ev);
        z += w;
        ushort4 hv = *(const ushort4*)(Hp + (size_t)src * 256);
        a0 += w * bf2f(hv.x); a1 += w * bf2f(hv.y);
        a2 += w * bf2f(hv.z); a3 += w * bf2f(hv.w);
    }
    float inv = 1.f / (z + 1e-16f);
    *(float4*)&outp[(size_t)n * 256 + lane * 4] = make_float4(a0 * inv, a1 * inv, a2 * inv, a3 * inv);
}

// ---------------- layer 2: aggregation + head-mean + bias + log_softmax ----------------
__global__ __launch_bounds__(256) void k_agg2(const unsigned short* __restrict__ H2,
        const float* __restrict__ es, const float* __restrict__ ed,
        const int* __restrict__ indptr, const int* __restrict__ srcs,
        const float* __restrict__ b2, float* __restrict__ outp) {
    const int wid = threadIdx.x >> 6, lane = threadIdx.x & 63;
    const int n = blockIdx.x * 4 + wid;
    if (n >= NN) return;
    const bool act = lane < 40;
    const int head = lane / 10;                    // valid when act
    const float edh = act ? ed[n * 4 + head] : 0.f;
    const int e0 = indptr[n], e1 = indptr[n + 1];
    float z = 0.f, acc[4] = {0.f, 0.f, 0.f, 0.f};
    const unsigned short* Hp = H2 + lane * 4;
    for (int e = e0; e < e1; ++e) {
        int src = srcs[e];
        if (act) {
            float ev = es[src * 4 + head] + edh;
            ev = (ev > 0.f) ? ev : 0.2f * ev;
            float w = __expf(ev);
            z += w;
            ushort4 hv = *(const ushort4*)(Hp + (size_t)src * 192);
            acc[0] += w * bf2f(hv.x); acc[1] += w * bf2f(hv.y);
            acc[2] += w * bf2f(hv.z); acc[3] += w * bf2f(hv.w);
        }
    }
    float inv = 1.f / (z + 1e-16f);
    float sv[4];
    #pragma unroll
    for (int j = 0; j < 4; j++) sv[j] = acc[j] * inv;
    // head mean into lanes 0..9 (sources: lane, lane+10, lane+20, lane+30)
    #pragma unroll
    for (int j = 0; j < 4; j++) {
        float v = sv[j];
        v += __shfl(sv[j], lane + 10);
        v += __shfl(sv[j], lane + 20);
        v += __shfl(sv[j], lane + 30);
        sv[j] = v;
    }
    const bool ol = lane < 10;
    float m4 = -1e30f;
    #pragma unroll
    for (int j = 0; j < 4; j++) {
        sv[j] = ol ? (0.25f * sv[j] + b2[lane * 4 + j]) : -1e30f;
        m4 = fmaxf(m4, sv[j]);
    }
    #pragma unroll
    for (int d = 1; d < 16; d <<= 1) m4 = fmaxf(m4, __shfl_xor(m4, d));
    float s = 0.f;
    #pragma unroll
    for (int j = 0; j < 4; j++) s += ol ? __expf(sv[j] - m4) : 0.f;
    #pragma unroll
    for (int d = 1; d < 16; d <<= 1) s += __shfl_xor(s, d);
    float ls = logf(s);
    if (ol) {
        float4 o = make_float4(sv[0] - m4 - ls, sv[1] - m4 - ls, sv[2] - m4 - ls, sv[3] - m4 - ls);
        *(float4*)&outp[(size_t)n * 40 + lane * 4] = o;
    }
}

// ---------------- BatchNorm stats + apply (fp32 in, bf16 out) ----------------
__global__ __launch_bounds__(256) void k_bnstats(const float* __restrict__ X,
        float* __restrict__ sum, float* __restrict__ sumsq) {
    const int col = threadIdx.x;
    float s = 0.f, q = 0.f;
    for (int r = blockIdx.x; r < NN; r += gridDim.x) {
        float v = X[(size_t)r * 256 + col];
        s += v; q += v * v;
    }
    atomicAdd(&sum[col], s);
    atomicAdd(&sumsq[col], q);
}

__global__ __launch_bounds__(256) void k_bnapply(const float* __restrict__ X,
        const float* __restrict__ sum, const float* __restrict__ sumsq,
        const float* __restrict__ g, const float* __restrict__ beta,
        unsigned short* __restrict__ Y) {
    const int col = threadIdx.x;
    const float inv = 1.f / (float)NN;
    float mu = sum[col] * inv;
    float var = sumsq[col] * inv - mu * mu;
    float sc = rsqrtf(var + 1e-5f) * g[col];
    float sh = beta[col] - mu * sc;                 // GAT bias b cancels under BN
    for (int r = blockIdx.x; r < NN; r += gridDim.x) {
        float v = X[(size_t)r * 256 + col] * sc + sh;
        v = (v > 0.f) ? v : expm1f(v);              // ELU
        Y[(size_t)r * 256 + col] = f2bf(v);
    }
}

extern "C" void kernel_launch(void* const* d_in, const int* in_sizes, int n_in,
                              void* d_out, int out_size, void* d_ws, size_t ws_size,
                              hipStream_t stream) {
    const float* x   = (const float*)d_in[0];
    const int*   ei  = (const int*)d_in[1];
    const float* W0  = (const float*)d_in[2];
    const float* as0 = (const float*)d_in[3];
    const float* ad0 = (const float*)d_in[4];
    const float* g0  = (const float*)d_in[6];
    const float* be0 = (const float*)d_in[7];
    const float* W1  = (const float*)d_in[8];
    const float* as1 = (const float*)d_in[9];
    const float* ad1 = (const float*)d_in[10];
    const float* g1  = (const float*)d_in[12];
    const float* be1 = (const float*)d_in[13];
    const float* W2  = (const float*)d_in[14];
    const float* as2 = (const float*)d_in[15];
    const float* ad2 = (const float*)d_in[16];
    const float* b2  = (const float*)d_in[17];
    float* out = (float*)d_out;

    char* w = (char*)d_ws;
    size_t off = 0;
    auto take = [&](size_t bytes) -> void* {
        off = (off + 255) & ~(size_t)255;
        void* p = w + off; off += bytes; return p;
    };
    // shared region: xb (12.8MB, dies after L0 gemm) aliased under Bb16 (25.6MB)
    unsigned short* Bb16 = (unsigned short*)take((size_t)NN * 256 * 2);
    unsigned short* xb   = Bb16;
    unsigned short* H16  = (unsigned short*)take((size_t)NN * 256 * 2);  // also L2's stride-192 buf
    float* Bb     = (float*)take((size_t)NN * 256 * 4);
    float* es     = (float*)take((size_t)NN * 4 * 4);
    float* ed     = (float*)take((size_t)NN * 4 * 4);
    int*   counts = (int*)take((size_t)NN * 4);
    int*   indptr = (int*)take((size_t)(NN + 1) * 4);
    int*   cursor = (int*)take((size_t)NN * 4);
    int*   srcs   = (int*)take((size_t)NEP * 4);
    unsigned short* Wt0 = (unsigned short*)take((size_t)256 * 128 * 2);
    unsigned short* Wt1 = (unsigned short*)take((size_t)256 * 256 * 2);
    unsigned short* Wt2 = (unsigned short*)take((size_t)192 * 256 * 2);
    float* bns = (float*)take(512 * 4);

    const int gE = (NEP + 255) / 256;
    hipMemsetAsync(counts, 0, (size_t)NN * 4, stream);
    k_count  <<<gE, 256, 0, stream>>>(ei, counts);
    k_scan   <<<1, 1024, 0, stream>>>(counts, indptr, cursor);
    k_scatter<<<gE, 256, 0, stream>>>(ei, cursor, srcs);

    k_f2b<<<(NN * 128 / 4 + 255) / 256, 256, 0, stream>>>(x, xb, NN * 128 / 4);
    k_wt<<<(256 * 128 + 255) / 256, 256, 0, stream>>>(W0, Wt0, 128, 256, 256);
    k_wt<<<(256 * 256 + 255) / 256, 256, 0, stream>>>(W1, Wt1, 256, 256, 256);
    k_wt<<<(192 * 256 + 255) / 256, 256, 0, stream>>>(W2, Wt2, 256, 160, 192);

    const int gM = (NN + 63) / 64;       // 782
    const int gW = (NN + 3) / 4;         // 12500 (waves/nodes per block = 4)

    // ---- layer 0 ----
    k_gemm<128, 256><<<dim3(gM, 4), 256, 0, stream>>>(xb, Wt0, H16);
    k_edot01<<<gW, 256, 0, stream>>>(H16, as0, ad0, es, ed);
    k_agg<<<gW, 256, 0, stream>>>(H16, es, ed, indptr, srcs, Bb);
    hipMemsetAsync(bns, 0, 2048, stream);
    k_bnstats<<<512, 256, 0, stream>>>(Bb, bns, bns + 256);
    k_bnapply<<<1024, 256, 0, stream>>>(Bb, bns, bns + 256, g0, be0, Bb16);

    // ---- layer 1 ----
    k_gemm<256, 256><<<dim3(gM, 4), 256, 0, stream>>>(Bb16, Wt1, H16);
    k_edot01<<<gW, 256, 0, stream>>>(H16, as1, ad1, es, ed);
    k_agg<<<gW, 256, 0, stream>>>(H16, es, ed, indptr, srcs, Bb);
    hipMemsetAsync(bns, 0, 2048, stream);
    k_bnstats<<<512, 256, 0, stream>>>(Bb, bns, bns + 256);
    k_bnapply<<<1024, 256, 0, stream>>>(Bb, bns, bns + 256, g1, be1, Bb16);

    // ---- layer 2 ----
    k_gemm<256, 192><<<dim3(gM, 3), 256, 0, stream>>>(Bb16, Wt2, H16);
    k_edot2<<<gW, 256, 0, stream>>>(H16, as2, ad2, es, ed);
    k_agg2<<<gW, 256, 0, stream>>>(H16, es, ed, indptr, srcs, b2, out);
}

// Round 3
// 575.395 us; speedup vs baseline: 1.6271x; 1.2627x over previous
//
#include <hip/hip_runtime.h>

#define NN 50000
#define EE 800000
#define NEP (EE + NN)

typedef float f32x4 __attribute__((ext_vector_type(4)));
typedef short bf16x8 __attribute__((ext_vector_type(8)));

__device__ inline float bf2f(unsigned short u) {
    union { unsigned int i; float f; } v; v.i = ((unsigned int)u) << 16; return v.f;
}
__device__ inline unsigned short f2bf(float f) {
    unsigned int x = __builtin_bit_cast(unsigned int, f);
    unsigned int r = x + 0x7FFFu + ((x >> 16) & 1u);
    return (unsigned short)(r >> 16);
}

// ---------------- CSR build (counting sort by dst) ----------------
__global__ __launch_bounds__(256) void k_count(const int* __restrict__ ei, int* __restrict__ counts) {
    int e = blockIdx.x * 256 + threadIdx.x;
    if (e >= NEP) return;
    int dst = (e < EE) ? ei[EE + e] : (e - EE);
    atomicAdd(&counts[dst], 1);
}

__global__ __launch_bounds__(1024) void k_scan(const int* __restrict__ counts,
                                               int* __restrict__ indptr, int* __restrict__ cursor) {
    __shared__ int wsum[16];
    __shared__ int carry_s;
    int tid = threadIdx.x, lane = tid & 63, wid = tid >> 6;
    if (tid == 0) carry_s = 0;
    __syncthreads();
    for (int base = 0; base < NN; base += 1024) {
        int i = base + tid;
        int v = (i < NN) ? counts[i] : 0;
        int s = v;
        #pragma unroll
        for (int d = 1; d < 64; d <<= 1) { int t = __shfl_up(s, d); if (lane >= d) s += t; }
        if (lane == 63) wsum[wid] = s;
        __syncthreads();
        if (wid == 0) {
            int ws = (lane < 16) ? wsum[lane] : 0;
            #pragma unroll
            for (int d = 1; d < 16; d <<= 1) { int t = __shfl_up(ws, d); if (lane >= d) ws += t; }
            if (lane < 16) wsum[lane] = ws;
        }
        __syncthreads();
        int off = carry_s + (wid > 0 ? wsum[wid - 1] : 0);
        int excl = off + s - v;
        if (i < NN) { indptr[i] = excl; cursor[i] = excl; }
        __syncthreads();
        if (tid == 1023) carry_s = off + s;
        __syncthreads();
    }
    if (tid == 0) indptr[NN] = carry_s;
}

__global__ __launch_bounds__(256) void k_scatter(const int* __restrict__ ei,
                                                 int* __restrict__ cursor,
                                                 int* __restrict__ srcs, int* __restrict__ dsts) {
    int e = blockIdx.x * 256 + threadIdx.x;
    if (e >= NEP) return;
    int src, dst;
    if (e < EE) { src = ei[e]; dst = ei[EE + e]; }
    else        { src = e - EE; dst = src; }
    int pos = atomicAdd(&cursor[dst], 1);
    srcs[pos] = src;
    dsts[pos] = dst;
}

// ---------------- fp32 -> bf16 convert (x) ----------------
__global__ __launch_bounds__(256) void k_f2b(const float* __restrict__ X,
                                             unsigned short* __restrict__ Y, int n4) {
    int i = blockIdx.x * 256 + threadIdx.x;
    if (i >= n4) return;
    float4 v = ((const float4*)X)[i];
    ushort4 o;
    o.x = f2bf(v.x); o.y = f2bf(v.y); o.z = f2bf(v.z); o.w = f2bf(v.w);
    ((ushort4*)Y)[i] = o;
}

// ---------------- W[k][c] -> Wt[c][k] bf16 (pad cols to NOP with zeros) ----------------
__global__ __launch_bounds__(256) void k_wt(const float* __restrict__ W,
                                            unsigned short* __restrict__ Wt,
                                            int K, int NO, int NOP) {
    int idx = blockIdx.x * 256 + threadIdx.x;
    if (idx >= NOP * K) return;
    int c = idx / K, k = idx - c * K;
    float v = (c < NO) ? W[(size_t)k * NO + c] : 0.f;
    Wt[idx] = f2bf(v);
}

// ---------------- bf16 MFMA GEMM: Y[NN,NOUTP](bf16) = Xb[NN,K](bf16) @ Wt^T ----------------
// Block = 64 rows x full NOUTP (loop over 64-col groups). A staged whole-K once in LDS
// with XOR swizzle (granule ^= row&7). 4 waves = 2Mx2N; wave does 2x2 frags of 16x16x32.
template<int K, int NOUTP>
__global__ __launch_bounds__(256) void k_gemm(const unsigned short* __restrict__ Xb,
                                              const unsigned short* __restrict__ Wt,
                                              unsigned short* __restrict__ Y) {
    constexpr int G = K / 8;
    __shared__ __attribute__((aligned(16))) unsigned short As[64 * K];
    const int bm = blockIdx.x * 64;
    const int tid = threadIdx.x, lane = tid & 63, wid = tid >> 6;
    const int wm = wid >> 1, wn = wid & 1;
    const int l15 = lane & 15, l4 = lane >> 4;

    #pragma unroll
    for (int i = 0; i < (64 * G) / 256; i++) {
        int p = tid + 256 * i;
        int row = p / G, gi = p % G;
        int grow = bm + row; if (grow >= NN) grow = 0;
        bf16x8 v = *(const bf16x8*)&Xb[(size_t)grow * K + gi * 8];
        *(bf16x8*)&As[row * K + (gi ^ (row & 7)) * 8] = v;
    }
    __syncthreads();

    #pragma unroll
    for (int bg = 0; bg < NOUTP / 64; bg++) {
        const int bn = bg * 64;
        bf16x8 bfr[2][K / 32];
        #pragma unroll
        for (int n = 0; n < 2; n++) {
            const int col = bn + wn * 32 + n * 16 + l15;
            #pragma unroll
            for (int ks = 0; ks < K / 32; ks++)
                bfr[n][ks] = *(const bf16x8*)&Wt[(size_t)col * K + ks * 32 + l4 * 8];
        }
        f32x4 acc[2][2];
        #pragma unroll
        for (int m = 0; m < 2; m++)
            #pragma unroll
            for (int n = 0; n < 2; n++) acc[m][n] = (f32x4)0.f;
        #pragma unroll
        for (int ks = 0; ks < K / 32; ks++) {
            #pragma unroll
            for (int m = 0; m < 2; m++) {
                const int r = wm * 32 + m * 16 + l15;
                const int pg = ((ks << 2) + l4) ^ (r & 7);
                bf16x8 af = *(const bf16x8*)&As[r * K + pg * 8];
                #pragma unroll
                for (int n = 0; n < 2; n++)
                    acc[m][n] = __builtin_amdgcn_mfma_f32_16x16x32_bf16(af, bfr[n][ks], acc[m][n], 0, 0, 0);
            }
        }
        #pragma unroll
        for (int m = 0; m < 2; m++) {
            const int row0 = bm + wm * 32 + m * 16 + l4 * 4;
            #pragma unroll
            for (int n = 0; n < 2; n++) {
                const int col = bn + wn * 32 + n * 16 + l15;
                #pragma unroll
                for (int j = 0; j < 4; j++) {
                    int gr = row0 + j;
                    if (gr < NN) Y[(size_t)gr * NOUTP + col] = f2bf(acc[m][n][j]);
                }
            }
        }
    }
}

// ---------------- attention logits (row stride 256, quarter-wave per node-head) ----------------
__global__ __launch_bounds__(256) void k_edot01(const unsigned short* __restrict__ H,
        const float* __restrict__ a_src, const float* __restrict__ a_dst,
        float* __restrict__ es, float* __restrict__ ed) {
    const int gw = (blockIdx.x * 256 + threadIdx.x) >> 6;
    const int lane = threadIdx.x & 63;
    if (gw >= NN) return;
    const int head = lane >> 4;
    ushort4 hv = *(const ushort4*)&H[(size_t)gw * 256 + lane * 4];
    float s1 = 0.f, s2 = 0.f;
    const unsigned short hvv[4] = {hv.x, hv.y, hv.z, hv.w};
    #pragma unroll
    for (int j = 0; j < 4; j++) {
        float v = bf2f(hvv[j]);
        s1 += v * a_src[lane * 4 + j];
        s2 += v * a_dst[lane * 4 + j];
    }
    #pragma unroll
    for (int d = 1; d < 16; d <<= 1) { s1 += __shfl_xor(s1, d); s2 += __shfl_xor(s2, d); }
    if ((lane & 15) == 0) { es[gw * 4 + head] = s1; ed[gw * 4 + head] = s2; }
}

__global__ __launch_bounds__(256) void k_edot2(const unsigned short* __restrict__ H2,
        const float* __restrict__ a_src, const float* __restrict__ a_dst,
        float* __restrict__ es, float* __restrict__ ed) {
    const int gw = (blockIdx.x * 256 + threadIdx.x) >> 6;
    const int lane = threadIdx.x & 63;
    if (gw >= NN) return;
    const int h = lane >> 4, g = lane & 15;
    float s1 = 0.f, s2 = 0.f;
    if (g < 10) {
        ushort4 hv = *(const ushort4*)&H2[(size_t)gw * 192 + h * 40 + g * 4];
        const unsigned short hvv[4] = {hv.x, hv.y, hv.z, hv.w};
        #pragma unroll
        for (int j = 0; j < 4; j++) {
            float v = bf2f(hvv[j]);
            s1 += v * a_src[h * 40 + g * 4 + j];
            s2 += v * a_dst[h * 40 + g * 4 + j];
        }
    }
    #pragma unroll
    for (int d = 1; d < 16; d <<= 1) { s1 += __shfl_xor(s1, d); s2 += __shfl_xor(s2, d); }
    if (g == 0) { es[gw * 4 + h] = s1; ed[gw * 4 + h] = s2; }
}

// ---------------- per-edge softmax weights (CSR order, edge-parallel) ----------------
__global__ __launch_bounds__(256) void k_wgt(const float4* __restrict__ es4,
        const float4* __restrict__ ed4, const int* __restrict__ srcs,
        const int* __restrict__ dsts, float4* __restrict__ wq) {
    int p = blockIdx.x * 256 + threadIdx.x;
    if (p >= NEP) return;
    float4 s = es4[srcs[p]];
    float4 d = ed4[dsts[p]];
    float e0 = s.x + d.x, e1 = s.y + d.y, e2 = s.z + d.z, e3 = s.w + d.w;
    e0 = (e0 > 0.f) ? e0 : 0.2f * e0;
    e1 = (e1 > 0.f) ? e1 : 0.2f * e1;
    e2 = (e2 > 0.f) ? e2 : 0.2f * e2;
    e3 = (e3 > 0.f) ? e3 : 0.2f * e3;
    wq[p] = make_float4(__expf(e0), __expf(e1), __expf(e2), __expf(e3));
}

// ---------------- fused aggregation, layers 0/1 (wave per node, unroll 4) ----------------
__global__ __launch_bounds__(256) void k_agg(const unsigned short* __restrict__ H,
        const float* __restrict__ wq,
        const int* __restrict__ indptr, const int* __restrict__ srcs,
        unsigned short* __restrict__ outp) {
    const int wid = threadIdx.x >> 6, lane = threadIdx.x & 63;
    const int n = blockIdx.x * 4 + wid;
    if (n >= NN) return;
    const int head = lane >> 4;
    const int e0 = indptr[n], e1 = indptr[n + 1];
    float z = 0.f, a0 = 0.f, a1 = 0.f, a2 = 0.f, a3 = 0.f;
    const unsigned short* Hp = H + lane * 4;
    int e = e0;
    for (; e + 4 <= e1; e += 4) {
        int s0 = srcs[e], s1 = srcs[e + 1], s2 = srcs[e + 2], s3 = srcs[e + 3];
        float w0 = wq[(size_t)e * 4 + head];
        float w1 = wq[(size_t)(e + 1) * 4 + head];
        float w2 = wq[(size_t)(e + 2) * 4 + head];
        float w3 = wq[(size_t)(e + 3) * 4 + head];
        ushort4 h0 = *(const ushort4*)(Hp + (size_t)s0 * 256);
        ushort4 h1 = *(const ushort4*)(Hp + (size_t)s1 * 256);
        ushort4 h2 = *(const ushort4*)(Hp + (size_t)s2 * 256);
        ushort4 h3 = *(const ushort4*)(Hp + (size_t)s3 * 256);
        z += (w0 + w1) + (w2 + w3);
        a0 += w0 * bf2f(h0.x) + w1 * bf2f(h1.x) + w2 * bf2f(h2.x) + w3 * bf2f(h3.x);
        a1 += w0 * bf2f(h0.y) + w1 * bf2f(h1.y) + w2 * bf2f(h2.y) + w3 * bf2f(h3.y);
        a2 += w0 * bf2f(h0.z) + w1 * bf2f(h1.z) + w2 * bf2f(h2.z) + w3 * bf2f(h3.z);
        a3 += w0 * bf2f(h0.w) + w1 * bf2f(h1.w) + w2 * bf2f(h2.w) + w3 * bf2f(h3.w);
    }
    for (; e < e1; ++e) {
        int s0 = srcs[e];
        float w0 = wq[(size_t)e * 4 + head];
        ushort4 h0 = *(const ushort4*)(Hp + (size_t)s0 * 256);
        z += w0;
        a0 += w0 * bf2f(h0.x); a1 += w0 * bf2f(h0.y);
        a2 += w0 * bf2f(h0.z); a3 += w0 * bf2f(h0.w);
    }
    float inv = 1.f / (z + 1e-16f);
    ushort4 o;
    o.x = f2bf(a0 * inv); o.y = f2bf(a1 * inv); o.z = f2bf(a2 * inv); o.w = f2bf(a3 * inv);
    *(ushort4*)&outp[(size_t)n * 256 + lane * 4] = o;
}

// ---------------- layer 2: aggregation + head-mean + bias + log_softmax ----------------
__global__ __launch_bounds__(256) void k_agg2(const unsigned short* __restrict__ H2,
        const float* __restrict__ wq,
        const int* __restrict__ indptr, const int* __restrict__ srcs,
        const float* __restrict__ b2, float* __restrict__ outp) {
    const int wid = threadIdx.x >> 6, lane = threadIdx.x & 63;
    const int n = blockIdx.x * 4 + wid;
    if (n >= NN) return;
    const bool act = lane < 40;
    const int head = lane / 10;
    const int e0 = indptr[n], e1 = indptr[n + 1];
    float z = 0.f, acc[4] = {0.f, 0.f, 0.f, 0.f};
    const unsigned short* Hp = H2 + lane * 4;
    int e = e0;
    if (act) {
        for (; e + 4 <= e1; e += 4) {
            int s0 = srcs[e], s1 = srcs[e + 1], s2 = srcs[e + 2], s3 = srcs[e + 3];
            float w0 = wq[(size_t)e * 4 + head];
            float w1 = wq[(size_t)(e + 1) * 4 + head];
            float w2 = wq[(size_t)(e + 2) * 4 + head];
            float w3 = wq[(size_t)(e + 3) * 4 + head];
            ushort4 h0 = *(const ushort4*)(Hp + (size_t)s0 * 192);
            ushort4 h1 = *(const ushort4*)(Hp + (size_t)s1 * 192);
            ushort4 h2 = *(const ushort4*)(Hp + (size_t)s2 * 192);
            ushort4 h3 = *(const ushort4*)(Hp + (size_t)s3 * 192);
            z += (w0 + w1) + (w2 + w3);
            acc[0] += w0 * bf2f(h0.x) + w1 * bf2f(h1.x) + w2 * bf2f(h2.x) + w3 * bf2f(h3.x);
            acc[1] += w0 * bf2f(h0.y) + w1 * bf2f(h1.y) + w2 * bf2f(h2.y) + w3 * bf2f(h3.y);
            acc[2] += w0 * bf2f(h0.z) + w1 * bf2f(h1.z) + w2 * bf2f(h2.z) + w3 * bf2f(h3.z);
            acc[3] += w0 * bf2f(h0.w) + w1 * bf2f(h1.w) + w2 * bf2f(h2.w) + w3 * bf2f(h3.w);
        }
        for (; e < e1; ++e) {
            int s0 = srcs[e];
            float w0 = wq[(size_t)e * 4 + head];
            ushort4 h0 = *(const ushort4*)(Hp + (size_t)s0 * 192);
            z += w0;
            acc[0] += w0 * bf2f(h0.x); acc[1] += w0 * bf2f(h0.y);
            acc[2] += w0 * bf2f(h0.z); acc[3] += w0 * bf2f(h0.w);
        }
    }
    float inv = 1.f / (z + 1e-16f);
    float sv[4];
    #pragma unroll
    for (int j = 0; j < 4; j++) sv[j] = acc[j] * inv;
    #pragma unroll
    for (int j = 0; j < 4; j++) {
        float v = sv[j];
        v += __shfl(sv[j], lane + 10);
        v += __shfl(sv[j], lane + 20);
        v += __shfl(sv[j], lane + 30);
        sv[j] = v;
    }
    const bool ol = lane < 10;
    float m4 = -1e30f;
    #pragma unroll
    for (int j = 0; j < 4; j++) {
        sv[j] = ol ? (0.25f * sv[j] + b2[lane * 4 + j]) : -1e30f;
        m4 = fmaxf(m4, sv[j]);
    }
    #pragma unroll
    for (int d = 1; d < 16; d <<= 1) m4 = fmaxf(m4, __shfl_xor(m4, d));
    float s = 0.f;
    #pragma unroll
    for (int j = 0; j < 4; j++) s += ol ? __expf(sv[j] - m4) : 0.f;
    #pragma unroll
    for (int d = 1; d < 16; d <<= 1) s += __shfl_xor(s, d);
    float ls = logf(s);
    if (ol) {
        float4 o = make_float4(sv[0] - m4 - ls, sv[1] - m4 - ls, sv[2] - m4 - ls, sv[3] - m4 - ls);
        *(float4*)&outp[(size_t)n * 40 + lane * 4] = o;
    }
}

// ---------------- BatchNorm stats (bf16 in) + apply in-place (bf16) ----------------
__global__ __launch_bounds__(256) void k_bnstats(const unsigned short* __restrict__ X,
        float* __restrict__ sum, float* __restrict__ sumsq) {
    const int col = threadIdx.x;
    float s = 0.f, q = 0.f;
    for (int r = blockIdx.x; r < NN; r += gridDim.x) {
        float v = bf2f(X[(size_t)r * 256 + col]);
        s += v; q += v * v;
    }
    atomicAdd(&sum[col], s);
    atomicAdd(&sumsq[col], q);
}

__global__ __launch_bounds__(256) void k_bnapply(unsigned short* __restrict__ X,
        const float* __restrict__ sum, const float* __restrict__ sumsq,
        const float* __restrict__ g, const float* __restrict__ beta) {
    const int col = threadIdx.x;
    const float inv = 1.f / (float)NN;
    float mu = sum[col] * inv;
    float var = sumsq[col] * inv - mu * mu;
    float sc = rsqrtf(var + 1e-5f) * g[col];
    float sh = beta[col] - mu * sc;                 // GAT bias b cancels under BN
    for (int r = blockIdx.x; r < NN; r += gridDim.x) {
        float v = bf2f(X[(size_t)r * 256 + col]) * sc + sh;
        v = (v > 0.f) ? v : expm1f(v);              // ELU
        X[(size_t)r * 256 + col] = f2bf(v);
    }
}

extern "C" void kernel_launch(void* const* d_in, const int* in_sizes, int n_in,
                              void* d_out, int out_size, void* d_ws, size_t ws_size,
                              hipStream_t stream) {
    const float* x   = (const float*)d_in[0];
    const int*   ei  = (const int*)d_in[1];
    const float* W0  = (const float*)d_in[2];
    const float* as0 = (const float*)d_in[3];
    const float* ad0 = (const float*)d_in[4];
    const float* g0  = (const float*)d_in[6];
    const float* be0 = (const float*)d_in[7];
    const float* W1  = (const float*)d_in[8];
    const float* as1 = (const float*)d_in[9];
    const float* ad1 = (const float*)d_in[10];
    const float* g1  = (const float*)d_in[12];
    const float* be1 = (const float*)d_in[13];
    const float* W2  = (const float*)d_in[14];
    const float* as2 = (const float*)d_in[15];
    const float* ad2 = (const float*)d_in[16];
    const float* b2  = (const float*)d_in[17];
    float* out = (float*)d_out;

    char* w = (char*)d_ws;
    size_t off = 0;
    auto take = [&](size_t bytes) -> void* {
        off = (off + 255) & ~(size_t)255;
        void* p = w + off; off += bytes; return p;
    };
    unsigned short* Agg16 = (unsigned short*)take((size_t)NN * 256 * 2);  // agg out / BN in-place
    unsigned short* xb    = (unsigned short*)take((size_t)NN * 128 * 2);
    unsigned short* H16   = (unsigned short*)take((size_t)NN * 256 * 2);  // gemm out (L2: stride 192)
    float* es     = (float*)take((size_t)NN * 4 * 4);
    float* ed     = (float*)take((size_t)NN * 4 * 4);
    int*   counts = (int*)take((size_t)NN * 4);
    int*   indptr = (int*)take((size_t)(NN + 1) * 4);
    int*   cursor = (int*)take((size_t)NN * 4);
    int*   srcs   = (int*)take((size_t)NEP * 4);
    int*   dsts   = (int*)take((size_t)NEP * 4);
    float* wq     = (float*)take((size_t)NEP * 4 * 4);
    unsigned short* Wt0 = (unsigned short*)take((size_t)256 * 128 * 2);
    unsigned short* Wt1 = (unsigned short*)take((size_t)256 * 256 * 2);
    unsigned short* Wt2 = (unsigned short*)take((size_t)192 * 256 * 2);
    float* bns = (float*)take(512 * 4);

    const int gE = (NEP + 255) / 256;
    hipMemsetAsync(counts, 0, (size_t)NN * 4, stream);
    k_count  <<<gE, 256, 0, stream>>>(ei, counts);
    k_scan   <<<1, 1024, 0, stream>>>(counts, indptr, cursor);
    k_scatter<<<gE, 256, 0, stream>>>(ei, cursor, srcs, dsts);

    k_f2b<<<(NN * 128 / 4 + 255) / 256, 256, 0, stream>>>(x, xb, NN * 128 / 4);
    k_wt<<<(256 * 128 + 255) / 256, 256, 0, stream>>>(W0, Wt0, 128, 256, 256);
    k_wt<<<(256 * 256 + 255) / 256, 256, 0, stream>>>(W1, Wt1, 256, 256, 256);
    k_wt<<<(192 * 256 + 255) / 256, 256, 0, stream>>>(W2, Wt2, 256, 160, 192);

    const int gM = (NN + 63) / 64;       // 782
    const int gW = (NN + 3) / 4;         // 12500

    // ---- layer 0 ----
    k_gemm<128, 256><<<gM, 256, 0, stream>>>(xb, Wt0, H16);
    k_edot01<<<gW, 256, 0, stream>>>(H16, as0, ad0, es, ed);
    k_wgt<<<gE, 256, 0, stream>>>((const float4*)es, (const float4*)ed, srcs, dsts, (float4*)wq);
    k_agg<<<gW, 256, 0, stream>>>(H16, wq, indptr, srcs, Agg16);
    hipMemsetAsync(bns, 0, 2048, stream);
    k_bnstats<<<512, 256, 0, stream>>>(Agg16, bns, bns + 256);
    k_bnapply<<<1024, 256, 0, stream>>>(Agg16, bns, bns + 256, g0, be0);

    // ---- layer 1 ----
    k_gemm<256, 256><<<gM, 256, 0, stream>>>(Agg16, Wt1, H16);
    k_edot01<<<gW, 256, 0, stream>>>(H16, as1, ad1, es, ed);
    k_wgt<<<gE, 256, 0, stream>>>((const float4*)es, (const float4*)ed, srcs, dsts, (float4*)wq);
    k_agg<<<gW, 256, 0, stream>>>(H16, wq, indptr, srcs, Agg16);
    hipMemsetAsync(bns, 0, 2048, stream);
    k_bnstats<<<512, 256, 0, stream>>>(Agg16, bns, bns + 256);
    k_bnapply<<<1024, 256, 0, stream>>>(Agg16, bns, bns + 256, g1, be1);

    // ---- layer 2 ----
    k_gemm<256, 192><<<gM, 256, 0, stream>>>(Agg16, Wt2, H16);
    k_edot2<<<gW, 256, 0, stream>>>(H16, as2, ad2, es, ed);
    k_wgt<<<gE, 256, 0, stream>>>((const float4*)es, (const float4*)ed, srcs, dsts, (float4*)wq);
    k_agg2<<<gW, 256, 0, stream>>>(H16, wq, indptr, srcs, b2, out);
}